// Round 3
// baseline (629.041 us; speedup 1.0000x reference)
//
#include <hip/hip_runtime.h>

// DownSample — bf16 MFMA implicit-GEMM, gather form, zero-row trick.
// v4: occupancy lever. Wave tile 64x64 -> 32x64 (acc 64->32 AGPR, ~148->~100
//     unified regs, ~3 -> ~5 waves/SIMD) with v1's proven flat fully-unrolled
//     tap loop (v2/v3 showed hand-scheduling regresses). Plus bijective
//     XCD-chunked blockIdx swizzle (sorted rows => neighbor-slab L2 reuse).
//     Per-row memory traffic unchanged (m-split keeps one owner per row).
//
// Dense over all taps (27 conv / 8 pool); invalid neighbors index an appended
// all-zero row -> branch-free MFMA. fp32 accumulate, bn+relu fused in epilogue.
// Verified fragment mappings (gfx950 16x16x32 bf16):
//   A[m=lane&15][k=(lane>>4)*8+j]   B[k=(lane>>4)*8+j][n=lane&15]
//   C/D: n=lane&15, m=(lane>>4)*4+reg

#define NV 400000
#define ND 100000

typedef __attribute__((ext_vector_type(8))) short  bf16x8;
typedef __attribute__((ext_vector_type(4))) float  f32x4;

__device__ __forceinline__ unsigned short f2b(float f) {
    unsigned int u = __builtin_bit_cast(unsigned int, f);
    u += 0x7fffu + ((u >> 16) & 1u);          // round-to-nearest-even
    return (unsigned short)(u >> 16);
}

// ---- prep: fp32 -> bf16 bits, 4 at a time ---------------------------------
__global__ __launch_bounds__(256) void cvt_bf16_k(
    const float* __restrict__ in, unsigned short* __restrict__ out, int n)
{
    int t = (blockIdx.x * 256 + threadIdx.x) * 4;
    if (t >= n) return;
    float4 f = *(const float4*)(in + t);
    ushort4 u;
    u.x = f2b(f.x); u.y = f2b(f.y); u.z = f2b(f.z); u.w = f2b(f.w);
    *(ushort4*)(out + t) = u;
}

// ---- prep: pack W[nk][ci][64] fp32 into per-lane B fragments --------------
// layout: frag index ((k*steps + s)*4 + nt)*64 + lane, 8 bf16 each
__global__ __launch_bounds__(256) void pack_w_k(
    const float* __restrict__ W, unsigned short* __restrict__ out, int nk, int ci)
{
    int t = blockIdx.x * 256 + threadIdx.x;
    int steps = ci >> 5;
    if (t >= nk * steps * 4 * 64) return;
    int lane = t & 63;
    int nt   = (t >> 6) & 3;
    int rest = t >> 8;
    int s    = rest % steps;
    int k    = rest / steps;
    int col = lane & 15, quad = lane >> 4;
    int co = nt * 16 + col;
    unsigned short v[8];
#pragma unroll
    for (int j = 0; j < 8; ++j) {
        int cidx = s * 32 + quad * 8 + j;
        v[j] = f2b(W[((size_t)k * ci + cidx) * 64 + co]);
    }
    bf16x8 frag;
#pragma unroll
    for (int j = 0; j < 8; ++j) frag[j] = (short)v[j];
    *(bf16x8*)(out + (size_t)t * 8) = frag;
}

// ---- prep: invert kp maps -> ck[kk][parent] = child row (or NV sentinel) --
// transposed layout so the pool's j-loads are coalesced like the conv's
__global__ __launch_bounds__(256) void ck_init_k(int* __restrict__ ck)
{
    int t = blockIdx.x * 256 + threadIdx.x;
    if (t < ND * 8) ck[t] = NV;
}
__global__ __launch_bounds__(256) void ck_scatter_k(
    const int* __restrict__ kp_in, const int* __restrict__ kp_out,
    int* __restrict__ ck)
{
    int t = blockIdx.x * 256 + threadIdx.x;
    if (t >= 8 * NV) return;
    int j = kp_in[t];
    if (j == NV) return;
    int k = t / NV;
    ck[(size_t)k * ND + kp_out[t]] = j;
}

// ---- unified gather-GEMM: wave computes 32 rows x 64 channels -------------
// MODE: 0 = f32 out, 1 = bf16 out, 2 = both (outf + outb)
template <int CI, int NK, int MODE, int NR>
__global__ __launch_bounds__(256, 4) void conv_mfma(
    const unsigned short* __restrict__ xin,   // [(NV+1)][CI] bf16, row NV = 0
    const unsigned short* __restrict__ Wp,    // packed frags
    const int* __restrict__ km,               // [NK][NR], sentinel NV
    const float* __restrict__ bns, const float* __restrict__ bnb,
    float* __restrict__ outf, unsigned short* __restrict__ outb)
{
    constexpr int STEPS = CI / 32;
    const int lane = threadIdx.x & 63;
    const int wave = threadIdx.x >> 6;
    const int col = lane & 15, quad = lane >> 4;

    // bijective XCD-chunked swizzle (m204): works for any gridDim
    const int nwg = gridDim.x;
    const int q = nwg >> 3, r = nwg & 7;
    const int xcd = blockIdx.x & 7, bodd = blockIdx.x >> 3;
    const int bid = (xcd < r ? xcd * (q + 1) : r * (q + 1) + (xcd - r) * q) + bodd;

    const int wbase = (bid * 4 + wave) * 32;

    int rowm[2];
#pragma unroll
    for (int mt = 0; mt < 2; ++mt) {
        int rr = wbase + mt * 16 + col;
        rowm[mt] = rr < NR ? rr : NR - 1;
    }

    f32x4 acc[2][4];
#pragma unroll
    for (int mt = 0; mt < 2; ++mt)
#pragma unroll
        for (int nt = 0; nt < 4; ++nt) acc[mt][nt] = (f32x4)0.f;

    // flat fully-unrolled tap loop — compiler schedules loads across taps
    for (int k = 0; k < NK; ++k) {
        const int* __restrict__ kmr = km + (size_t)k * NR;
        int j[2];
#pragma unroll
        for (int mt = 0; mt < 2; ++mt) j[mt] = kmr[rowm[mt]];
#pragma unroll
        for (int s = 0; s < STEPS; ++s) {
            bf16x8 a[2];
#pragma unroll
            for (int mt = 0; mt < 2; ++mt)
                a[mt] = *(const bf16x8*)(xin + (size_t)j[mt] * CI + s * 32 + quad * 8);
            const unsigned short* bp = Wp + ((((size_t)k * STEPS + s) * 4) * 64 + lane) * 8;
#pragma unroll
            for (int nt = 0; nt < 4; ++nt) {
                bf16x8 b = *(const bf16x8*)(bp + (size_t)nt * 512);
#pragma unroll
                for (int mt = 0; mt < 2; ++mt)
                    acc[mt][nt] = __builtin_amdgcn_mfma_f32_16x16x32_bf16(
                        a[mt], b, acc[mt][nt], 0, 0, 0);
            }
        }
    }

    // ---- epilogue: bn + relu, store ----
#pragma unroll
    for (int nt = 0; nt < 4; ++nt) {
        const int n = nt * 16 + col;
        const float sc = bns[n], bi = bnb[n];
#pragma unroll
        for (int mt = 0; mt < 2; ++mt)
#pragma unroll
            for (int rr = 0; rr < 4; ++rr) {
                int row = wbase + mt * 16 + quad * 4 + rr;
                if (row < NR) {
                    float v = fmaxf(fmaf(acc[mt][nt][rr], sc, bi), 0.f);
                    if constexpr (MODE == 0) {
                        outf[(size_t)row * 64 + n] = v;
                    } else if constexpr (MODE == 1) {
                        outb[(size_t)row * 64 + n] = f2b(v);
                    } else {
                        outf[(size_t)row * 64 + n] = v;
                        outb[(size_t)row * 64 + n] = f2b(v);
                    }
                }
            }
    }
}

extern "C" void kernel_launch(void* const* d_in, const int* in_sizes, int n_in,
                              void* d_out, int out_size, void* d_ws, size_t ws_size,
                              hipStream_t stream)
{
    const float* x    = (const float*)d_in[0];
    const float* W1   = (const float*)d_in[1];
    const float* bn1s = (const float*)d_in[2];
    const float* bn1b = (const float*)d_in[3];
    const float* W2   = (const float*)d_in[4];
    const float* bn2s = (const float*)d_in[5];
    const float* bn2b = (const float*)d_in[6];
    const float* Wp   = (const float*)d_in[7];
    const float* bnps = (const float*)d_in[8];
    const float* bnpb = (const float*)d_in[9];
    const int* km_in  = (const int*)d_in[10];
    const int* kp_in  = (const int*)d_in[12];
    const int* kp_out = (const int*)d_in[13];

    float* down = (float*)d_out;                     // [NV,64] output 0
    float* pout = (float*)d_out + (size_t)NV * 64;   // [ND,64] output 1

    char* ws = (char*)d_ws;
    unsigned short* x_bf  = (unsigned short*)ws;  ws += (size_t)(NV + 1) * 32 * 2; // 25.6MB
    unsigned short* h_bf  = (unsigned short*)ws;  ws += (size_t)(NV + 1) * 64 * 2; // 51.2MB
    unsigned short* d_bf  = (unsigned short*)ws;  ws += (size_t)(NV + 1) * 64 * 2; // 51.2MB
    int*            ck    = (int*)ws;             ws += (size_t)8 * ND * 4;        // 3.2MB
    unsigned short* W1p   = (unsigned short*)ws;  ws += (size_t)27 * 32 * 64 * 2;
    unsigned short* W2p   = (unsigned short*)ws;  ws += (size_t)27 * 64 * 64 * 2;
    unsigned short* Wpp   = (unsigned short*)ws;

    // zero rows (re-poisoned to 0xAA before every timed call)
    hipMemsetAsync(x_bf + (size_t)NV * 32, 0, 32 * 2, stream);
    hipMemsetAsync(h_bf + (size_t)NV * 64, 0, 64 * 2, stream);
    hipMemsetAsync(d_bf + (size_t)NV * 64, 0, 64 * 2, stream);

    cvt_bf16_k<<<(NV * 32 / 4 + 255) / 256, 256, 0, stream>>>(x, x_bf, NV * 32);
    pack_w_k<<<(27 * 1 * 4 * 64 + 255) / 256, 256, 0, stream>>>(W1, W1p, 27, 32);
    pack_w_k<<<(27 * 2 * 4 * 64 + 255) / 256, 256, 0, stream>>>(W2, W2p, 27, 64);
    pack_w_k<<<(8  * 2 * 4 * 64 + 255) / 256, 256, 0, stream>>>(Wp, Wpp, 8, 64);
    ck_init_k<<<(ND * 8 + 255) / 256, 256, 0, stream>>>(ck);
    ck_scatter_k<<<(8 * NV + 255) / 256, 256, 0, stream>>>(kp_in, kp_out, ck);

    const int cgrid = (NV + 127) / 128;   // 32 rows/wave * 4 waves/block
    conv_mfma<32, 27, 1, NV><<<cgrid, 256, 0, stream>>>(
        x_bf, W1p, km_in, bn1s, bn1b, nullptr, h_bf);
    conv_mfma<64, 27, 2, NV><<<cgrid, 256, 0, stream>>>(
        h_bf, W2p, km_in, bn2s, bn2b, down, d_bf);
    conv_mfma<64, 8, 0, ND><<<(ND + 127) / 128, 256, 0, stream>>>(
        d_bf, Wpp, ck, bnps, bnpb, pout, nullptr);
}

// Round 4
// 587.136 us; speedup vs baseline: 1.0714x; 1.0714x over previous
//
#include <hip/hip_runtime.h>

// DownSample — bf16 MFMA implicit-GEMM, gather form, zero-row trick.
// v5: v1's exact structure (64-row wave tile, flat tap loop — best measured)
//     + B-fragments staged per-tap into LDS via global_load_lds, double-
//     buffered (one barrier/tap). Cuts per-tap vmem instrs 20->14 (conv2),
//     16->9 (conv1), and evicts the 221KB B stream from L1/TA entirely —
//     attacks the VMEM-request wall that v4's occupancy doubling proved
//     (2x waves, 0% speedup => request-throughput-bound, not latency-bound).
//     + bijective XCD swizzle (sorted rows => neighbor-slab L2 locality).
//
// Dense over all taps (27 conv / 8 pool); invalid neighbors index an appended
// all-zero row -> branch-free MFMA. fp32 accumulate, bn+relu fused in epilogue.
// Verified fragment mappings (gfx950 16x16x32 bf16):
//   A[m=lane&15][k=(lane>>4)*8+j]   B[k=(lane>>4)*8+j][n=lane&15]
//   C/D: n=lane&15, m=(lane>>4)*4+reg

#define NV 400000
#define ND 100000

typedef __attribute__((ext_vector_type(8))) short  bf16x8;
typedef __attribute__((ext_vector_type(4))) float  f32x4;

__device__ __forceinline__ unsigned short f2b(float f) {
    unsigned int u = __builtin_bit_cast(unsigned int, f);
    u += 0x7fffu + ((u >> 16) & 1u);          // round-to-nearest-even
    return (unsigned short)(u >> 16);
}

// ---- prep: fp32 -> bf16 bits, 4 at a time ---------------------------------
__global__ __launch_bounds__(256) void cvt_bf16_k(
    const float* __restrict__ in, unsigned short* __restrict__ out, int n)
{
    int t = (blockIdx.x * 256 + threadIdx.x) * 4;
    if (t >= n) return;
    float4 f = *(const float4*)(in + t);
    ushort4 u;
    u.x = f2b(f.x); u.y = f2b(f.y); u.z = f2b(f.z); u.w = f2b(f.w);
    *(ushort4*)(out + t) = u;
}

// ---- prep: pack W[nk][ci][64] fp32 into per-lane B fragments --------------
// layout: frag index ((k*steps + s)*4 + nt)*64 + lane, 8 bf16 each
__global__ __launch_bounds__(256) void pack_w_k(
    const float* __restrict__ W, unsigned short* __restrict__ out, int nk, int ci)
{
    int t = blockIdx.x * 256 + threadIdx.x;
    int steps = ci >> 5;
    if (t >= nk * steps * 4 * 64) return;
    int lane = t & 63;
    int nt   = (t >> 6) & 3;
    int rest = t >> 8;
    int s    = rest % steps;
    int k    = rest / steps;
    int col = lane & 15, quad = lane >> 4;
    int co = nt * 16 + col;
    unsigned short v[8];
#pragma unroll
    for (int j = 0; j < 8; ++j) {
        int cidx = s * 32 + quad * 8 + j;
        v[j] = f2b(W[((size_t)k * ci + cidx) * 64 + co]);
    }
    bf16x8 frag;
#pragma unroll
    for (int j = 0; j < 8; ++j) frag[j] = (short)v[j];
    *(bf16x8*)(out + (size_t)t * 8) = frag;
}

// ---- prep: invert kp maps -> ck[kk][parent] = child row (or NV sentinel) --
// transposed layout so the pool's j-loads are coalesced like the conv's
__global__ __launch_bounds__(256) void ck_init_k(int* __restrict__ ck)
{
    int t = blockIdx.x * 256 + threadIdx.x;
    if (t < ND * 8) ck[t] = NV;
}
__global__ __launch_bounds__(256) void ck_scatter_k(
    const int* __restrict__ kp_in, const int* __restrict__ kp_out,
    int* __restrict__ ck)
{
    int t = blockIdx.x * 256 + threadIdx.x;
    if (t >= 8 * NV) return;
    int j = kp_in[t];
    if (j == NV) return;
    int k = t / NV;
    ck[(size_t)k * ND + kp_out[t]] = j;
}

// ---- unified gather-GEMM: wave computes 64 rows x 64 channels -------------
// MODE: 0 = f32 out, 1 = bf16 out, 2 = both (outf + outb)
template <int CI, int NK, int MODE, int NR>
__global__ __launch_bounds__(256) void conv_mfma(
    const unsigned short* __restrict__ xin,   // [(NV+1)][CI] bf16, row NV = 0
    const unsigned short* __restrict__ Wp,    // packed frags
    const int* __restrict__ km,               // [NK][NR], sentinel NV
    const float* __restrict__ bns, const float* __restrict__ bnb,
    float* __restrict__ outf, unsigned short* __restrict__ outb)
{
    constexpr int STEPS = CI / 32;
    constexpr int FR = STEPS * 4;             // B fragments per tap
    __shared__ unsigned short bsh[2 * FR * 512];   // dbuf x FR frags x 64 lanes x 8

    const int lane = threadIdx.x & 63;
    const int wave = threadIdx.x >> 6;
    const int col = lane & 15, quad = lane >> 4;

    // bijective XCD-chunked swizzle (m204): works for any gridDim
    const int nwg = gridDim.x;
    const int q = nwg >> 3, r = nwg & 7;
    const int xcd = blockIdx.x & 7, bodd = blockIdx.x >> 3;
    const int bid = (xcd < r ? xcd * (q + 1) : r * (q + 1) + (xcd - r) * q) + bodd;

    const int wbase = (bid * 4 + wave) * 64;

    int rowm[4];
#pragma unroll
    for (int mt = 0; mt < 4; ++mt) {
        int rr = wbase + mt * 16 + col;
        rowm[mt] = rr < NR ? rr : NR - 1;
    }

    f32x4 acc[4][4];
#pragma unroll
    for (int mt = 0; mt < 4; ++mt)
#pragma unroll
        for (int nt = 0; nt < 4; ++nt) acc[mt][nt] = (f32x4)0.f;

    // stage tap k's B tile (FR KB) into LDS buffer b: waves split the frags,
    // dest = wave-uniform base + lane*16B == our packed layout exactly.
    auto stage = [&](int k, int b) {
#pragma unroll
        for (int f = wave; f < FR; f += 4) {
            const unsigned short* src = Wp + ((size_t)(k * FR + f) * 64 + lane) * 8;
            __builtin_amdgcn_global_load_lds(
                (const __attribute__((address_space(1))) void*)src,
                (__attribute__((address_space(3))) void*)&bsh[b * (FR * 512) + f * 512],
                16, 0, 0);
        }
    };

    stage(0, 0);
    int buf = 0;

    for (int k = 0; k < NK; ++k) {
        __syncthreads();                       // stage(k) complete (vmcnt drained)
        if (k + 1 < NK) stage(k + 1, buf ^ 1);

        const int* __restrict__ kmr = km + (size_t)k * NR;
        int j[4];
#pragma unroll
        for (int mt = 0; mt < 4; ++mt) j[mt] = kmr[rowm[mt]];

#pragma unroll
        for (int s = 0; s < STEPS; ++s) {
            bf16x8 a[4];
#pragma unroll
            for (int mt = 0; mt < 4; ++mt)
                a[mt] = *(const bf16x8*)(xin + (size_t)j[mt] * CI + s * 32 + quad * 8);
#pragma unroll
            for (int nt = 0; nt < 4; ++nt) {
                bf16x8 b = *(const bf16x8*)&bsh[buf * (FR * 512) + (s * 4 + nt) * 512 + lane * 8];
#pragma unroll
                for (int mt = 0; mt < 4; ++mt)
                    acc[mt][nt] = __builtin_amdgcn_mfma_f32_16x16x32_bf16(
                        a[mt], b, acc[mt][nt], 0, 0, 0);
            }
        }
        buf ^= 1;
    }

    // ---- epilogue: bn + relu, store ----
#pragma unroll
    for (int nt = 0; nt < 4; ++nt) {
        const int n = nt * 16 + col;
        const float sc = bns[n], bi = bnb[n];
#pragma unroll
        for (int mt = 0; mt < 4; ++mt)
#pragma unroll
            for (int rr = 0; rr < 4; ++rr) {
                int row = wbase + mt * 16 + quad * 4 + rr;
                if (row < NR) {
                    float v = fmaxf(fmaf(acc[mt][nt][rr], sc, bi), 0.f);
                    if constexpr (MODE == 0) {
                        outf[(size_t)row * 64 + n] = v;
                    } else if constexpr (MODE == 1) {
                        outb[(size_t)row * 64 + n] = f2b(v);
                    } else {
                        outf[(size_t)row * 64 + n] = v;
                        outb[(size_t)row * 64 + n] = f2b(v);
                    }
                }
            }
    }
}

extern "C" void kernel_launch(void* const* d_in, const int* in_sizes, int n_in,
                              void* d_out, int out_size, void* d_ws, size_t ws_size,
                              hipStream_t stream)
{
    const float* x    = (const float*)d_in[0];
    const float* W1   = (const float*)d_in[1];
    const float* bn1s = (const float*)d_in[2];
    const float* bn1b = (const float*)d_in[3];
    const float* W2   = (const float*)d_in[4];
    const float* bn2s = (const float*)d_in[5];
    const float* bn2b = (const float*)d_in[6];
    const float* Wp   = (const float*)d_in[7];
    const float* bnps = (const float*)d_in[8];
    const float* bnpb = (const float*)d_in[9];
    const int* km_in  = (const int*)d_in[10];
    const int* kp_in  = (const int*)d_in[12];
    const int* kp_out = (const int*)d_in[13];

    float* down = (float*)d_out;                     // [NV,64] output 0
    float* pout = (float*)d_out + (size_t)NV * 64;   // [ND,64] output 1

    char* ws = (char*)d_ws;
    unsigned short* x_bf  = (unsigned short*)ws;  ws += (size_t)(NV + 1) * 32 * 2; // 25.6MB
    unsigned short* h_bf  = (unsigned short*)ws;  ws += (size_t)(NV + 1) * 64 * 2; // 51.2MB
    unsigned short* d_bf  = (unsigned short*)ws;  ws += (size_t)(NV + 1) * 64 * 2; // 51.2MB
    int*            ck    = (int*)ws;             ws += (size_t)8 * ND * 4;        // 3.2MB
    unsigned short* W1p   = (unsigned short*)ws;  ws += (size_t)27 * 32 * 64 * 2;
    unsigned short* W2p   = (unsigned short*)ws;  ws += (size_t)27 * 64 * 64 * 2;
    unsigned short* Wpp   = (unsigned short*)ws;

    // zero rows (re-poisoned to 0xAA before every timed call)
    hipMemsetAsync(x_bf + (size_t)NV * 32, 0, 32 * 2, stream);
    hipMemsetAsync(h_bf + (size_t)NV * 64, 0, 64 * 2, stream);
    hipMemsetAsync(d_bf + (size_t)NV * 64, 0, 64 * 2, stream);

    cvt_bf16_k<<<(NV * 32 / 4 + 255) / 256, 256, 0, stream>>>(x, x_bf, NV * 32);
    pack_w_k<<<(27 * 1 * 4 * 64 + 255) / 256, 256, 0, stream>>>(W1, W1p, 27, 32);
    pack_w_k<<<(27 * 2 * 4 * 64 + 255) / 256, 256, 0, stream>>>(W2, W2p, 27, 64);
    pack_w_k<<<(8  * 2 * 4 * 64 + 255) / 256, 256, 0, stream>>>(Wp, Wpp, 8, 64);
    ck_init_k<<<(ND * 8 + 255) / 256, 256, 0, stream>>>(ck);
    ck_scatter_k<<<(8 * NV + 255) / 256, 256, 0, stream>>>(kp_in, kp_out, ck);

    const int cgrid = (NV + 255) / 256;
    conv_mfma<32, 27, 1, NV><<<cgrid, 256, 0, stream>>>(
        x_bf, W1p, km_in, bn1s, bn1b, nullptr, h_bf);
    conv_mfma<64, 27, 2, NV><<<cgrid, 256, 0, stream>>>(
        h_bf, W2p, km_in, bn2s, bn2b, down, d_bf);
    conv_mfma<64, 8, 0, ND><<<(ND + 255) / 256, 256, 0, stream>>>(
        d_bf, Wpp, ck, bnps, bnpb, pout, nullptr);
}